// Round 22
// baseline (442.630 us; speedup 1.0000x reference)
//
#include <hip/hip_runtime.h>
#include <math.h>

// Problem dims
#define BT 64       // B*N sequences
#define T 256
#define DM 128      // d_model
#define DI 256      // d_inner
#define DS 16       // d_state
#define DR 8        // dt_rank
#define M_ROWS (BT*T)   // 16384
#define NC 16       // time chunks for parallel scan
#define CL (T/NC)   // chunk length = 16

typedef __attribute__((ext_vector_type(8))) short short8v;   // 8 bf16
typedef __attribute__((ext_vector_type(4))) float f32x4;     // MFMA acc
typedef __attribute__((ext_vector_type(4))) unsigned int uint4v;
union U8 { unsigned int u[4]; uint4v v; short8v s; };

__device__ __forceinline__ float fast_silu(float x) {
  return x * __builtin_amdgcn_rcpf(1.0f + __expf(-x));
}
__device__ __forceinline__ float softplus_f(float x) {
  return fmaxf(x, 0.0f) + __logf(1.0f + __expf(-fabsf(x)));
}

// exact 3-way bf16 split of 8 fp32 (truncation; subtractions exact)
__device__ __forceinline__ void split3(const float* x, short8v& o1, short8v& o2, short8v& o3) {
  unsigned int h1[8], h2[8], h3[8];
#pragma unroll
  for (int e = 0; e < 8; e++) {
    const float xe = x[e];
    const unsigned int a = __float_as_uint(xe) & 0xFFFF0000u;
    const float r1 = xe - __uint_as_float(a);
    const unsigned int b = __float_as_uint(r1) & 0xFFFF0000u;
    const float r2 = r1 - __uint_as_float(b);
    const unsigned int c = __float_as_uint(r2) & 0xFFFF0000u;
    h1[e] = a; h2[e] = b; h3[e] = c;
  }
  U8 u1, u2, u3;
#pragma unroll
  for (int q = 0; q < 4; q++) {
    u1.u[q] = (h1[2 * q] >> 16) | (h1[2 * q + 1] & 0xFFFF0000u);
    u2.u[q] = (h2[2 * q] >> 16) | (h2[2 * q + 1] & 0xFFFF0000u);
    u3.u[q] = (h3[2 * q] >> 16) | (h3[2 * q + 1] & 0xFFFF0000u);
  }
  o1 = u1.s; o2 = u2.s; o3 = u3.s;
}

// ---------------- unified weight prep: split all 3 weight mats into frag-direct planes ---
__global__ __launch_bounds__(64) void prep_all(
    const float* __restrict__ in_w, const float* __restrict__ xw,
    const float* __restrict__ dtw, const float* __restrict__ ow,
    unsigned int* __restrict__ pw1, unsigned int* __restrict__ pwb,
    unsigned int* __restrict__ pow_) {
  const int b = blockIdx.x;
  const int l = threadIdx.x;
  const int rA = l & 15, kg = l >> 4;
  float x[8];
  unsigned int* dst;
  size_t base;
  if (b < 256) {            // in_w: [128,512] per layer, Kt=4, NF=32
    const int layer = b >> 7, rem = b & 127;
    const int ks = rem >> 5, cf = rem & 31;
    const int col = cf * 16 + rA, k0 = ks * 32 + kg * 8;
    const float* W = in_w + (size_t)layer * 128 * 512;
#pragma unroll
    for (int e = 0; e < 8; e++) x[e] = W[(size_t)(k0 + e) * 512 + col];
    dst = pw1 + (size_t)layer * 98304;
    base = (((size_t)ks * 32 + cf) * 64 + l) * 4;
    short8v p1, p2, p3; split3(x, p1, p2, p3);
    U8 t;
    t.s = p1; *reinterpret_cast<uint4v*>(dst + base) = t.v;
    t.s = p2; *reinterpret_cast<uint4v*>(dst + 32768 + base) = t.v;
    t.s = p3; *reinterpret_cast<uint4v*>(dst + 65536 + base) = t.v;
  } else if (b < 576) {     // W_big: [256,320] per layer (inline), Kt=8, NF=20
    const int bb = b - 256;
    const int layer = bb / 160, rem = bb % 160;
    const int ks = rem / 20, cf = rem % 20;
    const int col = cf * 16 + rA, k0 = ks * 32 + kg * 8;
    const float* xwl = xw + (size_t)layer * DI * 40;
    const float* dtwl = dtw + (size_t)layer * DR * DI;
#pragma unroll
    for (int e = 0; e < 8; e++) {
      const int k = k0 + e;
      float v = 0.f;
      if (col < 256) {
#pragma unroll
        for (int r = 0; r < DR; r++) v += xwl[k * 40 + r] * dtwl[r * DI + col];
      } else if (col < 288) {
        v = xwl[k * 40 + 8 + (col - 256)];
      }
      x[e] = v;
    }
    dst = pwb + (size_t)layer * 122880;
    base = (((size_t)ks * 20 + cf) * 64 + l) * 4;
    short8v p1, p2, p3; split3(x, p1, p2, p3);
    U8 t;
    t.s = p1; *reinterpret_cast<uint4v*>(dst + base) = t.v;
    t.s = p2; *reinterpret_cast<uint4v*>(dst + 40960 + base) = t.v;
    t.s = p3; *reinterpret_cast<uint4v*>(dst + 81920 + base) = t.v;
  } else {                  // ow: [256,128] per layer, Kt=8, NF=8
    const int bb = b - 576;
    const int layer = bb >> 6, rem = bb & 63;
    const int ks = rem >> 3, cf = rem & 7;
    const int col = cf * 16 + rA, k0 = ks * 32 + kg * 8;
    const float* W = ow + (size_t)layer * 256 * 128;
#pragma unroll
    for (int e = 0; e < 8; e++) x[e] = W[(size_t)(k0 + e) * 128 + col];
    dst = pow_ + (size_t)layer * 49152;
    base = (((size_t)ks * 8 + cf) * 64 + l) * 4;
    short8v p1, p2, p3; split3(x, p1, p2, p3);
    U8 t;
    t.s = p1; *reinterpret_cast<uint4v*>(dst + base) = t.v;
    t.s = p2; *reinterpret_cast<uint4v*>(dst + 16384 + base) = t.v;
    t.s = p3; *reinterpret_cast<uint4v*>(dst + 32768 + base) = t.v;
  }
}

// ---------------- MFMA split-bf16 GEMM: A fp32 row-major, split3 in-register -------------
// __launch_bounds__(256, 8): measured VGPR=48 fits the 64-cap -> 8 waves/SIMD residency
// (2x round-20's TLP for latency hiding). Round-11 spill signature (VGPR~32 + WRITE
// inflation) is the revert trigger.
// XCD-chunked swizzle: tile = (bid&7)*cpx + (bid>>3), grid must be 8*cpx blocks.
// EPI=0: plain fp32 store. EPI=1: DBC epilogue; last column-wave (wc0==256) skips j>=2
//   (pad cols 288..319, discarded). EPI=3: gemm1, res half (col>=256) stored silu'd.
template <int FR, int CF, int EPI>
__global__ __launch_bounds__(256, 8) void gemm_mfma(
    const float* __restrict__ Af, const unsigned int* __restrict__ Bp,
    float* __restrict__ C, float* __restrict__ Bb, float* __restrict__ Cb,
    const float* __restrict__ dtb, int M, int Nn, int K, int cpx) {
  const int NWC = Nn / (16 * CF);
  const int tile = (blockIdx.x & 7) * cpx + (blockIdx.x >> 3);
  const int wid = tile * 4 + (threadIdx.x >> 6);
  const int l = threadIdx.x & 63;
  const int mw = wid / NWC, nw = wid % NWC;
  const int wr0 = mw * (16 * FR), wc0 = nw * (16 * CF);
  const int rA = l & 15, kg = l >> 4;
  const int NF = Nn / 16, Kt = K >> 5;
  const bool lastw = (EPI == 1) && (wc0 == 256);   // wave-uniform

  f32x4 acc[FR][CF];
#pragma unroll
  for (int fr = 0; fr < FR; fr++)
#pragma unroll
    for (int j = 0; j < CF; j++) acc[fr][j] = (f32x4){0.f, 0.f, 0.f, 0.f};

  for (int ks = 0; ks < Kt; ks++) {
    short8v bf[3][CF];
#pragma unroll
    for (int p = 0; p < 3; p++)
#pragma unroll
      for (int j = 0; j < CF; j++) {
        if (lastw && j >= 2) continue;     // pad columns, discarded
        U8 t;
        t.v = *reinterpret_cast<const uint4v*>(
            Bp + ((((size_t)p * Kt + ks) * NF + (wc0 >> 4) + j) * 64 + l) * 4);
        bf[p][j] = t.s;
      }
#pragma unroll
    for (int fr = 0; fr < FR; fr++) {
      const float* ap = Af + (size_t)(wr0 + fr * 16 + rA) * K + ks * 32 + kg * 8;
      float x[8];
      *reinterpret_cast<float4*>(x) = *reinterpret_cast<const float4*>(ap);
      *reinterpret_cast<float4*>(x + 4) = *reinterpret_cast<const float4*>(ap + 4);
      short8v a1, a2, a3;
      split3(x, a1, a2, a3);
#pragma unroll
      for (int j = 0; j < CF; j++) {
        if (lastw && j >= 2) continue;
        f32x4 c = acc[fr][j];
        c = __builtin_amdgcn_mfma_f32_16x16x32_bf16(a1, bf[0][j], c, 0, 0, 0);
        c = __builtin_amdgcn_mfma_f32_16x16x32_bf16(a1, bf[1][j], c, 0, 0, 0);
        c = __builtin_amdgcn_mfma_f32_16x16x32_bf16(a2, bf[0][j], c, 0, 0, 0);
        c = __builtin_amdgcn_mfma_f32_16x16x32_bf16(a1, bf[2][j], c, 0, 0, 0);
        c = __builtin_amdgcn_mfma_f32_16x16x32_bf16(a3, bf[0][j], c, 0, 0, 0);
        c = __builtin_amdgcn_mfma_f32_16x16x32_bf16(a2, bf[1][j], c, 0, 0, 0);
        acc[fr][j] = c;
      }
    }
  }

  const int cr = (l >> 4) * 4;
  const int cc = l & 15;
  if (EPI == 0) {
#pragma unroll
    for (int fr = 0; fr < FR; fr++)
#pragma unroll
      for (int j = 0; j < CF; j++) {
        const int col = wc0 + j * 16 + cc;
#pragma unroll
        for (int r = 0; r < 4; r++)
          C[(size_t)(wr0 + fr * 16 + cr + r) * Nn + col] = acc[fr][j][r];
      }
  } else if (EPI == 1) {
#pragma unroll
    for (int fr = 0; fr < FR; fr++)
#pragma unroll
      for (int j = 0; j < CF; j++) {
        const int col = wc0 + j * 16 + cc;
        if (col < 256) {
          const float bias = dtb[col];
#pragma unroll
          for (int r = 0; r < 4; r++)
            C[(size_t)(wr0 + fr * 16 + cr + r) * DI + col] =
                softplus_f(acc[fr][j][r] + bias);
        } else if (col < 272) {
#pragma unroll
          for (int r = 0; r < 4; r++)
            Bb[(size_t)(wr0 + fr * 16 + cr + r) * DS + (col - 256)] = acc[fr][j][r];
        } else if (col < 288) {
#pragma unroll
          for (int r = 0; r < 4; r++)
            Cb[(size_t)(wr0 + fr * 16 + cr + r) * DS + (col - 272)] = acc[fr][j][r];
        }
      }
  } else {  // EPI == 3: gemm1 — res half (col>=256) stored pre-silu'd
#pragma unroll
    for (int fr = 0; fr < FR; fr++)
#pragma unroll
      for (int j = 0; j < CF; j++) {
        const int col = wc0 + j * 16 + cc;
        if (col < 256) {
#pragma unroll
          for (int r = 0; r < 4; r++)
            C[(size_t)(wr0 + fr * 16 + cr + r) * Nn + col] = acc[fr][j][r];
        } else {
#pragma unroll
          for (int r = 0; r < 4; r++)
            C[(size_t)(wr0 + fr * 16 + cr + r) * Nn + col] = fast_silu(acc[fr][j][r]);
        }
      }
  }
}

// ---------------- depthwise causal conv + bias + silu -> fp32 u only ----------------
__global__ __launch_bounds__(256) void conv_silu_kernel(
    const float* __restrict__ xzr,
    const float* __restrict__ cw, const float* __restrict__ cb,
    float* __restrict__ u) {
  const int d = threadIdx.x;
  const int m0 = blockIdx.x * 8;
  const int t0 = m0 & (T - 1);
  const float4 cv = *reinterpret_cast<const float4*>(&cw[d * 4]);
  const float bias = cb[d];
  float w0 = 0.f, w1 = 0.f, w2 = 0.f;
  if (t0 != 0) {
    w0 = xzr[(size_t)(m0 - 3) * 512 + d];
    w1 = xzr[(size_t)(m0 - 2) * 512 + d];
    w2 = xzr[(size_t)(m0 - 1) * 512 + d];
  }
#pragma unroll
  for (int i = 0; i < 8; i++) {
    const size_t m = m0 + i;
    const float cur = xzr[m * 512 + d];
    const float a = bias + cv.x * w0 + cv.y * w1 + cv.z * w2 + cv.w * cur;
    u[m * DI + d] = fast_silu(a);
    w0 = w1; w1 = w2; w2 = cur;
  }
}

// ---------------- fused chunked scan: phase1 + combine + phase3 in one kernel ------------
__global__ __launch_bounds__(1024) void scan_fused(
    const float* __restrict__ delta, const float* __restrict__ u,
    const float* __restrict__ Bb, const float* __restrict__ Cb,
    const float* __restrict__ xz,            // res half pre-silu'd by gemm1
    const float* __restrict__ A_log, const float* __restrict__ Dp,
    float* __restrict__ g) {
  __shared__ float sH[DS][NC][64];   // 64 KB
  __shared__ float sS[NC][64];       // 4 KB
  const int bt = blockIdx.x;         // 0..63
  const int dq = blockIdx.y;         // 0..3
  const int tid = threadIdx.x;
  const int c  = tid >> 6;           // 0..15
  const int dl = tid & 63;
  const int d  = dq * 64 + dl;

  float An[16];
  const float4* al = reinterpret_cast<const float4*>(&A_log[d * DS]);
#pragma unroll
  for (int q = 0; q < 4; q++) {
    float4 a = al[q];
    An[q * 4 + 0] = -__expf(a.x);
    An[q * 4 + 1] = -__expf(a.y);
    An[q * 4 + 2] = -__expf(a.z);
    An[q * 4 + 3] = -__expf(a.w);
  }

  // ---- phase 1: chunk-local scan from h=0 ----
  float h[16];
#pragma unroll
  for (int n = 0; n < 16; n++) h[n] = 0.f;
  float Sdl = 0.f;

  const size_t m0 = (size_t)bt * T + c * CL;
  for (int t = 0; t < CL; t++) {
    const size_t m = m0 + t;
    const float dlv = delta[m * DI + d];
    const float uu = u[m * DI + d];
    const float du = dlv * uu;
    Sdl += dlv;
    const float4* bp = reinterpret_cast<const float4*>(&Bb[m * DS]);
    const float4 B0 = bp[0], B1 = bp[1], B2 = bp[2], B3 = bp[3];
    const float Bv[16] = {B0.x, B0.y, B0.z, B0.w, B1.x, B1.y, B1.z, B1.w,
                          B2.x, B2.y, B2.z, B2.w, B3.x, B3.y, B3.z, B3.w};
#pragma unroll
    for (int n = 0; n < 16; n++) {
      const float dA = __expf(dlv * An[n]);
      h[n] = dA * h[n] + du * Bv[n];
    }
  }
#pragma unroll
  for (int n = 0; n < 16; n++) sH[n][c][dl] = h[n];
  sS[c][dl] = Sdl;
  __syncthreads();

  // ---- combine: thread (n2, dl2) runs the serial 16-chunk recurrence ----
  {
    const int n2 = tid >> 6;       // 0..15
    const int dl2 = tid & 63;
    const int d2 = dq * 64 + dl2;
    const float An2 = -__expf(A_log[d2 * DS + n2]);
    float hin = 0.f;
#pragma unroll
    for (int cc = 0; cc < NC; cc++) {
      const float sdl = sS[cc][dl2];
      const float Hv = sH[n2][cc][dl2];
      sH[n2][cc][dl2] = hin;       // h at entry of chunk cc
      hin = __expf(An2 * sdl) * hin + Hv;
    }
  }
  __syncthreads();

  // ---- phase 3: rescan from true h0; emit g ----
#pragma unroll
  for (int n = 0; n < 16; n++) h[n] = sH[n][c][dl];
  const float Dpd = Dp[d];

  for (int t = 0; t < CL; t++) {
    const size_t m = m0 + t;
    const float dlv = delta[m * DI + d];
    const float uu = u[m * DI + d];
    const float du = dlv * uu;
    const float4* bp = reinterpret_cast<const float4*>(&Bb[m * DS]);
    const float4 B0 = bp[0], B1 = bp[1], B2 = bp[2], B3 = bp[3];
    const float4* cp = reinterpret_cast<const float4*>(&Cb[m * DS]);
    const float4 C0 = cp[0], C1 = cp[1], C2 = cp[2], C3 = cp[3];
    const float Bv[16] = {B0.x, B0.y, B0.z, B0.w, B1.x, B1.y, B1.z, B1.w,
                          B2.x, B2.y, B2.z, B2.w, B3.x, B3.y, B3.z, B3.w};
    const float Cv[16] = {C0.x, C0.y, C0.z, C0.w, C1.x, C1.y, C1.z, C1.w,
                          C2.x, C2.y, C2.z, C2.w, C3.x, C3.y, C3.z, C3.w};
    float y = 0.f;
#pragma unroll
    for (int n = 0; n < 16; n++) {
      const float dA = __expf(dlv * An[n]);
      h[n] = dA * h[n] + du * Bv[n];
      y += h[n] * Cv[n];
    }
    const float rs = xz[m * 512 + 256 + d];       // already silu'd (gemm1 EPI=3)
    g[m * DI + d] = (y + uu * Dpd) * rs;          // aliases delta (same-thread RAW only)
  }
}

// ---------------- launch ----------------
extern "C" void kernel_launch(void* const* d_in, const int* in_sizes, int n_in,
                              void* d_out, int out_size, void* d_ws, size_t ws_size,
                              hipStream_t stream) {
  const float* x      = (const float*)d_in[0];
  const float* in_w   = (const float*)d_in[1];   // [2,128,512]
  const float* conv_w = (const float*)d_in[2];   // [2,256,1,4]
  const float* conv_b = (const float*)d_in[3];   // [2,256]
  const float* xw     = (const float*)d_in[4];   // [2,256,40]
  const float* dtw    = (const float*)d_in[5];   // [2,8,256]
  const float* dtb    = (const float*)d_in[6];   // [2,256]
  const float* A_log  = (const float*)d_in[7];   // [2,256,16]
  const float* Dp     = (const float*)d_in[8];   // [2,256]
  const float* ow     = (const float*)d_in[9];   // [2,256,128]
  float* out = (float*)d_out;
  float* ws  = (float*)d_ws;

  float* xz = ws;                          // 16384*512
  float* u  = ws + 8388608;                // 16384*256 fp32
  float* dg = ws + 12582912;               // 16384*256 (delta, then g alias)
  float* Bb = ws + 16777216;               // 16384*16
  float* Cb = ws + 17039360;               // 16384*16
  float* hb = ws + 17301504;               // 16384*128, ends 19398656
  unsigned int* pl_w1 = (unsigned int*)(ws + 27787264);  // 2 x 98304 u32
  unsigned int* pl_wb = (unsigned int*)(ws + 27983872);  // 2 x 122880
  unsigned int* pl_ow = (unsigned int*)(ws + 28229632);  // 2 x 49152, ends 28327936

  prep_all<<<704, 64, 0, stream>>>(in_w, xw, dtw, ow, pl_w1, pl_wb, pl_ow);

  for (int l = 0; l < 2; l++) {
    const float* Ain = (l == 0) ? x : hb;
    float* dst = (l == 1) ? out : hb;

    // gemm1: [16384,128]@[128,512] -> xz (res half silu'd). FR=1,CF=4: 2048 blocks
    gemm_mfma<1, 4, 3><<<2048, 256, 0, stream>>>(
        Ain, pl_w1 + (size_t)l * 98304, xz,
        nullptr, nullptr, nullptr, M_ROWS, 512, 128, 256);

    conv_silu_kernel<<<M_ROWS / 8, 256, 0, stream>>>(
        xz, conv_w + (size_t)l * DI * 4, conv_b + (size_t)l * DI, u);

    // DBC: [16384,256]@[256,320] -> delta/B/C. FR=1,CF=4: 1280 blocks
    gemm_mfma<1, 4, 1><<<1280, 256, 0, stream>>>(
        u, pl_wb + (size_t)l * 122880, dg, Bb, Cb, dtb + (size_t)l * DI,
        M_ROWS, 320, 256, 160);

    // fused scan: 64 bt x 4 dquads, 1024 threads (16 chunks x 64 d), H in LDS
    scan_fused<<<dim3(BT, 4), 1024, 0, stream>>>(
        dg, u, Bb, Cb, xz, A_log + (size_t)l * DI * DS, Dp + (size_t)l * DI,
        dg);

    // gemm3: [16384,256]@[256,128] -> dst. FR=1,CF=4: 512 blocks
    gemm_mfma<1, 4, 0><<<512, 256, 0, stream>>>(
        dg, pl_ow + (size_t)l * 49152, dst, nullptr, nullptr, nullptr,
        M_ROWS, 128, 256, 64);
  }
}

// Round 23
// 223.972 us; speedup vs baseline: 1.9763x; 1.9763x over previous
//
#include <hip/hip_runtime.h>
#include <math.h>

// Problem dims
#define BT 64       // B*N sequences
#define T 256
#define DM 128      // d_model
#define DI 256      // d_inner
#define DS 16       // d_state
#define DR 8        // dt_rank
#define M_ROWS (BT*T)   // 16384
#define NC 16       // time chunks for parallel scan
#define CL (T/NC)   // chunk length = 16

typedef __attribute__((ext_vector_type(8))) short short8v;   // 8 bf16
typedef __attribute__((ext_vector_type(4))) float f32x4;     // MFMA acc
typedef __attribute__((ext_vector_type(4))) unsigned int uint4v;
union U8 { unsigned int u[4]; uint4v v; short8v s; };

__device__ __forceinline__ float fast_silu(float x) {
  return x * __builtin_amdgcn_rcpf(1.0f + __expf(-x));
}
__device__ __forceinline__ float softplus_f(float x) {
  return fmaxf(x, 0.0f) + __logf(1.0f + __expf(-fabsf(x)));
}

// exact 3-way bf16 split of 8 fp32 (truncation; subtractions exact)
__device__ __forceinline__ void split3(const float* x, short8v& o1, short8v& o2, short8v& o3) {
  unsigned int h1[8], h2[8], h3[8];
#pragma unroll
  for (int e = 0; e < 8; e++) {
    const float xe = x[e];
    const unsigned int a = __float_as_uint(xe) & 0xFFFF0000u;
    const float r1 = xe - __uint_as_float(a);
    const unsigned int b = __float_as_uint(r1) & 0xFFFF0000u;
    const float r2 = r1 - __uint_as_float(b);
    const unsigned int c = __float_as_uint(r2) & 0xFFFF0000u;
    h1[e] = a; h2[e] = b; h3[e] = c;
  }
  U8 u1, u2, u3;
#pragma unroll
  for (int q = 0; q < 4; q++) {
    u1.u[q] = (h1[2 * q] >> 16) | (h1[2 * q + 1] & 0xFFFF0000u);
    u2.u[q] = (h2[2 * q] >> 16) | (h2[2 * q + 1] & 0xFFFF0000u);
    u3.u[q] = (h3[2 * q] >> 16) | (h3[2 * q + 1] & 0xFFFF0000u);
  }
  o1 = u1.s; o2 = u2.s; o3 = u3.s;
}

// ---------------- unified weight prep: split all 3 weight mats into frag-direct planes ---
__global__ __launch_bounds__(64) void prep_all(
    const float* __restrict__ in_w, const float* __restrict__ xw,
    const float* __restrict__ dtw, const float* __restrict__ ow,
    unsigned int* __restrict__ pw1, unsigned int* __restrict__ pwb,
    unsigned int* __restrict__ pow_) {
  const int b = blockIdx.x;
  const int l = threadIdx.x;
  const int rA = l & 15, kg = l >> 4;
  float x[8];
  unsigned int* dst;
  size_t base;
  if (b < 256) {            // in_w: [128,512] per layer, Kt=4, NF=32
    const int layer = b >> 7, rem = b & 127;
    const int ks = rem >> 5, cf = rem & 31;
    const int col = cf * 16 + rA, k0 = ks * 32 + kg * 8;
    const float* W = in_w + (size_t)layer * 128 * 512;
#pragma unroll
    for (int e = 0; e < 8; e++) x[e] = W[(size_t)(k0 + e) * 512 + col];
    dst = pw1 + (size_t)layer * 98304;
    base = (((size_t)ks * 32 + cf) * 64 + l) * 4;
    short8v p1, p2, p3; split3(x, p1, p2, p3);
    U8 t;
    t.s = p1; *reinterpret_cast<uint4v*>(dst + base) = t.v;
    t.s = p2; *reinterpret_cast<uint4v*>(dst + 32768 + base) = t.v;
    t.s = p3; *reinterpret_cast<uint4v*>(dst + 65536 + base) = t.v;
  } else if (b < 576) {     // W_big: [256,320] per layer (inline), Kt=8, NF=20
    const int bb = b - 256;
    const int layer = bb / 160, rem = bb % 160;
    const int ks = rem / 20, cf = rem % 20;
    const int col = cf * 16 + rA, k0 = ks * 32 + kg * 8;
    const float* xwl = xw + (size_t)layer * DI * 40;
    const float* dtwl = dtw + (size_t)layer * DR * DI;
#pragma unroll
    for (int e = 0; e < 8; e++) {
      const int k = k0 + e;
      float v = 0.f;
      if (col < 256) {
#pragma unroll
        for (int r = 0; r < DR; r++) v += xwl[k * 40 + r] * dtwl[r * DI + col];
      } else if (col < 288) {
        v = xwl[k * 40 + 8 + (col - 256)];
      }
      x[e] = v;
    }
    dst = pwb + (size_t)layer * 122880;
    base = (((size_t)ks * 20 + cf) * 64 + l) * 4;
    short8v p1, p2, p3; split3(x, p1, p2, p3);
    U8 t;
    t.s = p1; *reinterpret_cast<uint4v*>(dst + base) = t.v;
    t.s = p2; *reinterpret_cast<uint4v*>(dst + 40960 + base) = t.v;
    t.s = p3; *reinterpret_cast<uint4v*>(dst + 81920 + base) = t.v;
  } else {                  // ow: [256,128] per layer, Kt=8, NF=8
    const int bb = b - 576;
    const int layer = bb >> 6, rem = bb & 63;
    const int ks = rem >> 3, cf = rem & 7;
    const int col = cf * 16 + rA, k0 = ks * 32 + kg * 8;
    const float* W = ow + (size_t)layer * 256 * 128;
#pragma unroll
    for (int e = 0; e < 8; e++) x[e] = W[(size_t)(k0 + e) * 128 + col];
    dst = pow_ + (size_t)layer * 49152;
    base = (((size_t)ks * 8 + cf) * 64 + l) * 4;
    short8v p1, p2, p3; split3(x, p1, p2, p3);
    U8 t;
    t.s = p1; *reinterpret_cast<uint4v*>(dst + base) = t.v;
    t.s = p2; *reinterpret_cast<uint4v*>(dst + 16384 + base) = t.v;
    t.s = p3; *reinterpret_cast<uint4v*>(dst + 32768 + base) = t.v;
  }
}

// ---------------- MFMA split-bf16 GEMM: A fp32 row-major, split3 in-register -------------
// XCD-chunked swizzle: tile = (bid&7)*cpx + (bid>>3), grid must be 8*cpx blocks.
// __launch_bounds__(256,4): VGPR 48 natural, NO lower cap (rounds 11/22 spill lesson).
// EPI=0: plain fp32 store. EPI=1: DBC epilogue; last column-wave (wc0==256) skips j>=2
//   (pad cols 288..319, discarded). EPI=3: gemm1, res half (col>=256) stored silu'd.
template <int FR, int CF, int EPI>
__global__ __launch_bounds__(256, 4) void gemm_mfma(
    const float* __restrict__ Af, const unsigned int* __restrict__ Bp,
    float* __restrict__ C, float* __restrict__ Bb, float* __restrict__ Cb,
    const float* __restrict__ dtb, int M, int Nn, int K, int cpx) {
  const int NWC = Nn / (16 * CF);
  const int tile = (blockIdx.x & 7) * cpx + (blockIdx.x >> 3);
  const int wid = tile * 4 + (threadIdx.x >> 6);
  const int l = threadIdx.x & 63;
  const int mw = wid / NWC, nw = wid % NWC;
  const int wr0 = mw * (16 * FR), wc0 = nw * (16 * CF);
  const int rA = l & 15, kg = l >> 4;
  const int NF = Nn / 16, Kt = K >> 5;
  const bool lastw = (EPI == 1) && (wc0 == 256);   // wave-uniform

  f32x4 acc[FR][CF];
#pragma unroll
  for (int fr = 0; fr < FR; fr++)
#pragma unroll
    for (int j = 0; j < CF; j++) acc[fr][j] = (f32x4){0.f, 0.f, 0.f, 0.f};

  for (int ks = 0; ks < Kt; ks++) {
    short8v bf[3][CF];
#pragma unroll
    for (int p = 0; p < 3; p++)
#pragma unroll
      for (int j = 0; j < CF; j++) {
        if (lastw && j >= 2) continue;     // pad columns, discarded
        U8 t;
        t.v = *reinterpret_cast<const uint4v*>(
            Bp + ((((size_t)p * Kt + ks) * NF + (wc0 >> 4) + j) * 64 + l) * 4);
        bf[p][j] = t.s;
      }
#pragma unroll
    for (int fr = 0; fr < FR; fr++) {
      const float* ap = Af + (size_t)(wr0 + fr * 16 + rA) * K + ks * 32 + kg * 8;
      float x[8];
      *reinterpret_cast<float4*>(x) = *reinterpret_cast<const float4*>(ap);
      *reinterpret_cast<float4*>(x + 4) = *reinterpret_cast<const float4*>(ap + 4);
      short8v a1, a2, a3;
      split3(x, a1, a2, a3);
#pragma unroll
      for (int j = 0; j < CF; j++) {
        if (lastw && j >= 2) continue;
        f32x4 c = acc[fr][j];
        c = __builtin_amdgcn_mfma_f32_16x16x32_bf16(a1, bf[0][j], c, 0, 0, 0);
        c = __builtin_amdgcn_mfma_f32_16x16x32_bf16(a1, bf[1][j], c, 0, 0, 0);
        c = __builtin_amdgcn_mfma_f32_16x16x32_bf16(a2, bf[0][j], c, 0, 0, 0);
        c = __builtin_amdgcn_mfma_f32_16x16x32_bf16(a1, bf[2][j], c, 0, 0, 0);
        c = __builtin_amdgcn_mfma_f32_16x16x32_bf16(a3, bf[0][j], c, 0, 0, 0);
        c = __builtin_amdgcn_mfma_f32_16x16x32_bf16(a2, bf[1][j], c, 0, 0, 0);
        acc[fr][j] = c;
      }
    }
  }

  const int cr = (l >> 4) * 4;
  const int cc = l & 15;
  if (EPI == 0) {
#pragma unroll
    for (int fr = 0; fr < FR; fr++)
#pragma unroll
      for (int j = 0; j < CF; j++) {
        const int col = wc0 + j * 16 + cc;
#pragma unroll
        for (int r = 0; r < 4; r++)
          C[(size_t)(wr0 + fr * 16 + cr + r) * Nn + col] = acc[fr][j][r];
      }
  } else if (EPI == 1) {
#pragma unroll
    for (int fr = 0; fr < FR; fr++)
#pragma unroll
      for (int j = 0; j < CF; j++) {
        const int col = wc0 + j * 16 + cc;
        if (col < 256) {
          const float bias = dtb[col];
#pragma unroll
          for (int r = 0; r < 4; r++)
            C[(size_t)(wr0 + fr * 16 + cr + r) * DI + col] =
                softplus_f(acc[fr][j][r] + bias);
        } else if (col < 272) {
#pragma unroll
          for (int r = 0; r < 4; r++)
            Bb[(size_t)(wr0 + fr * 16 + cr + r) * DS + (col - 256)] = acc[fr][j][r];
        } else if (col < 288) {
#pragma unroll
          for (int r = 0; r < 4; r++)
            Cb[(size_t)(wr0 + fr * 16 + cr + r) * DS + (col - 272)] = acc[fr][j][r];
        }
      }
  } else {  // EPI == 3: gemm1 — res half (col>=256) stored pre-silu'd
#pragma unroll
    for (int fr = 0; fr < FR; fr++)
#pragma unroll
      for (int j = 0; j < CF; j++) {
        const int col = wc0 + j * 16 + cc;
        if (col < 256) {
#pragma unroll
          for (int r = 0; r < 4; r++)
            C[(size_t)(wr0 + fr * 16 + cr + r) * Nn + col] = acc[fr][j][r];
        } else {
#pragma unroll
          for (int r = 0; r < 4; r++)
            C[(size_t)(wr0 + fr * 16 + cr + r) * Nn + col] = fast_silu(acc[fr][j][r]);
        }
      }
  }
}

// ---------------- depthwise causal conv + bias + silu -> fp32 u only ----------------
__global__ __launch_bounds__(256) void conv_silu_kernel(
    const float* __restrict__ xzr,
    const float* __restrict__ cw, const float* __restrict__ cb,
    float* __restrict__ u) {
  const int d = threadIdx.x;
  const int m0 = blockIdx.x * 8;
  const int t0 = m0 & (T - 1);
  const float4 cv = *reinterpret_cast<const float4*>(&cw[d * 4]);
  const float bias = cb[d];
  float w0 = 0.f, w1 = 0.f, w2 = 0.f;
  if (t0 != 0) {
    w0 = xzr[(size_t)(m0 - 3) * 512 + d];
    w1 = xzr[(size_t)(m0 - 2) * 512 + d];
    w2 = xzr[(size_t)(m0 - 1) * 512 + d];
  }
#pragma unroll
  for (int i = 0; i < 8; i++) {
    const size_t m = m0 + i;
    const float cur = xzr[m * 512 + d];
    const float a = bias + cv.x * w0 + cv.y * w1 + cv.z * w2 + cv.w * cur;
    u[m * DI + d] = fast_silu(a);
    w0 = w1; w1 = w2; w2 = cur;
  }
}

// ---------------- fused chunked scan: phase1 + combine + phase3 in one kernel ------------
__global__ __launch_bounds__(1024) void scan_fused(
    const float* __restrict__ delta, const float* __restrict__ u,
    const float* __restrict__ Bb, const float* __restrict__ Cb,
    const float* __restrict__ xz,            // res half pre-silu'd by gemm1
    const float* __restrict__ A_log, const float* __restrict__ Dp,
    float* __restrict__ g) {
  __shared__ float sH[DS][NC][64];   // 64 KB
  __shared__ float sS[NC][64];       // 4 KB
  const int bt = blockIdx.x;         // 0..63
  const int dq = blockIdx.y;         // 0..3
  const int tid = threadIdx.x;
  const int c  = tid >> 6;           // 0..15
  const int dl = tid & 63;
  const int d  = dq * 64 + dl;

  float An[16];
  const float4* al = reinterpret_cast<const float4*>(&A_log[d * DS]);
#pragma unroll
  for (int q = 0; q < 4; q++) {
    float4 a = al[q];
    An[q * 4 + 0] = -__expf(a.x);
    An[q * 4 + 1] = -__expf(a.y);
    An[q * 4 + 2] = -__expf(a.z);
    An[q * 4 + 3] = -__expf(a.w);
  }

  // ---- phase 1: chunk-local scan from h=0 ----
  float h[16];
#pragma unroll
  for (int n = 0; n < 16; n++) h[n] = 0.f;
  float Sdl = 0.f;

  const size_t m0 = (size_t)bt * T + c * CL;
  for (int t = 0; t < CL; t++) {
    const size_t m = m0 + t;
    const float dlv = delta[m * DI + d];
    const float uu = u[m * DI + d];
    const float du = dlv * uu;
    Sdl += dlv;
    const float4* bp = reinterpret_cast<const float4*>(&Bb[m * DS]);
    const float4 B0 = bp[0], B1 = bp[1], B2 = bp[2], B3 = bp[3];
    const float Bv[16] = {B0.x, B0.y, B0.z, B0.w, B1.x, B1.y, B1.z, B1.w,
                          B2.x, B2.y, B2.z, B2.w, B3.x, B3.y, B3.z, B3.w};
#pragma unroll
    for (int n = 0; n < 16; n++) {
      const float dA = __expf(dlv * An[n]);
      h[n] = dA * h[n] + du * Bv[n];
    }
  }
#pragma unroll
  for (int n = 0; n < 16; n++) sH[n][c][dl] = h[n];
  sS[c][dl] = Sdl;
  __syncthreads();

  // ---- combine: thread (n2, dl2) runs the serial 16-chunk recurrence ----
  {
    const int n2 = tid >> 6;       // 0..15
    const int dl2 = tid & 63;
    const int d2 = dq * 64 + dl2;
    const float An2 = -__expf(A_log[d2 * DS + n2]);
    float hin = 0.f;
#pragma unroll
    for (int cc = 0; cc < NC; cc++) {
      const float sdl = sS[cc][dl2];
      const float Hv = sH[n2][cc][dl2];
      sH[n2][cc][dl2] = hin;       // h at entry of chunk cc
      hin = __expf(An2 * sdl) * hin + Hv;
    }
  }
  __syncthreads();

  // ---- phase 3: rescan from true h0; emit g ----
#pragma unroll
  for (int n = 0; n < 16; n++) h[n] = sH[n][c][dl];
  const float Dpd = Dp[d];

  for (int t = 0; t < CL; t++) {
    const size_t m = m0 + t;
    const float dlv = delta[m * DI + d];
    const float uu = u[m * DI + d];
    const float du = dlv * uu;
    const float4* bp = reinterpret_cast<const float4*>(&Bb[m * DS]);
    const float4 B0 = bp[0], B1 = bp[1], B2 = bp[2], B3 = bp[3];
    const float4* cp = reinterpret_cast<const float4*>(&Cb[m * DS]);
    const float4 C0 = cp[0], C1 = cp[1], C2 = cp[2], C3 = cp[3];
    const float Bv[16] = {B0.x, B0.y, B0.z, B0.w, B1.x, B1.y, B1.z, B1.w,
                          B2.x, B2.y, B2.z, B2.w, B3.x, B3.y, B3.z, B3.w};
    const float Cv[16] = {C0.x, C0.y, C0.z, C0.w, C1.x, C1.y, C1.z, C1.w,
                          C2.x, C2.y, C2.z, C2.w, C3.x, C3.y, C3.z, C3.w};
    float y = 0.f;
#pragma unroll
    for (int n = 0; n < 16; n++) {
      const float dA = __expf(dlv * An[n]);
      h[n] = dA * h[n] + du * Bv[n];
      y += h[n] * Cv[n];
    }
    const float rs = xz[m * 512 + 256 + d];       // already silu'd (gemm1 EPI=3)
    g[m * DI + d] = (y + uu * Dpd) * rs;          // aliases delta (same-thread RAW only)
  }
}

// ---------------- launch ----------------
extern "C" void kernel_launch(void* const* d_in, const int* in_sizes, int n_in,
                              void* d_out, int out_size, void* d_ws, size_t ws_size,
                              hipStream_t stream) {
  const float* x      = (const float*)d_in[0];
  const float* in_w   = (const float*)d_in[1];   // [2,128,512]
  const float* conv_w = (const float*)d_in[2];   // [2,256,1,4]
  const float* conv_b = (const float*)d_in[3];   // [2,256]
  const float* xw     = (const float*)d_in[4];   // [2,256,40]
  const float* dtw    = (const float*)d_in[5];   // [2,8,256]
  const float* dtb    = (const float*)d_in[6];   // [2,256]
  const float* A_log  = (const float*)d_in[7];   // [2,256,16]
  const float* Dp     = (const float*)d_in[8];   // [2,256]
  const float* ow     = (const float*)d_in[9];   // [2,256,128]
  float* out = (float*)d_out;
  float* ws  = (float*)d_ws;

  float* xz = ws;                          // 16384*512
  float* u  = ws + 8388608;                // 16384*256 fp32
  float* dg = ws + 12582912;               // 16384*256 (delta, then g alias)
  float* Bb = ws + 16777216;               // 16384*16
  float* Cb = ws + 17039360;               // 16384*16
  float* hb = ws + 17301504;               // 16384*128, ends 19398656
  unsigned int* pl_w1 = (unsigned int*)(ws + 27787264);  // 2 x 98304 u32
  unsigned int* pl_wb = (unsigned int*)(ws + 27983872);  // 2 x 122880
  unsigned int* pl_ow = (unsigned int*)(ws + 28229632);  // 2 x 49152, ends 28327936

  prep_all<<<704, 64, 0, stream>>>(in_w, xw, dtw, ow, pl_w1, pl_wb, pl_ow);

  for (int l = 0; l < 2; l++) {
    const float* Ain = (l == 0) ? x : hb;
    float* dst = (l == 1) ? out : hb;

    // gemm1: [16384,128]@[128,512] -> xz (res half silu'd). FR=1,CF=4: 2048 blocks
    gemm_mfma<1, 4, 3><<<2048, 256, 0, stream>>>(
        Ain, pl_w1 + (size_t)l * 98304, xz,
        nullptr, nullptr, nullptr, M_ROWS, 512, 128, 256);

    conv_silu_kernel<<<M_ROWS / 8, 256, 0, stream>>>(
        xz, conv_w + (size_t)l * DI * 4, conv_b + (size_t)l * DI, u);

    // DBC: [16384,256]@[256,320] -> delta/B/C. FR=1,CF=4: 1280 blocks
    gemm_mfma<1, 4, 1><<<1280, 256, 0, stream>>>(
        u, pl_wb + (size_t)l * 122880, dg, Bb, Cb, dtb + (size_t)l * DI,
        M_ROWS, 320, 256, 160);

    // fused scan: 64 bt x 4 dquads, 1024 threads (16 chunks x 64 d), H in LDS
    scan_fused<<<dim3(BT, 4), 1024, 0, stream>>>(
        dg, u, Bb, Cb, xz, A_log + (size_t)l * DI * DS, Dp + (size_t)l * DI,
        dg);

    // gemm3: [16384,256]@[256,128] -> dst. FR=1,CF=4: 512 blocks
    gemm_mfma<1, 4, 0><<<512, 256, 0, stream>>>(
        dg, pl_ow + (size_t)l * 49152, dst, nullptr, nullptr, nullptr,
        M_ROWS, 128, 256, 64);
  }
}